// Round 1
// baseline (1417.162 us; speedup 1.0000x reference)
//
#include <hip/hip_runtime.h>
#include <math.h>

#define NB 4
#define C_ 256
#define NG 8
#define CPG 32
#define HW 4096
#define NH 4
#define HD 64
#define EPS 1e-5f

// ---------------- GroupNorm stats: one block per (b,g); group data is contiguous ----------------
__global__ __launch_bounds__(256) void gn_stats_k(const float* __restrict__ x,
                                                  float* __restrict__ stats) {
    int bg = blockIdx.x;  // 0..31
    const float4* base = (const float4*)(x + (size_t)bg * CPG * HW);
    const int n4 = CPG * HW / 4;  // 32768
    float s = 0.f, ss = 0.f;
    for (int i = threadIdx.x; i < n4; i += 256) {
        float4 v = base[i];
        s  += v.x + v.y + v.z + v.w;
        ss += v.x*v.x + v.y*v.y + v.z*v.z + v.w*v.w;
    }
    #pragma unroll
    for (int off = 32; off > 0; off >>= 1) {
        s  += __shfl_down(s, off);
        ss += __shfl_down(ss, off);
    }
    __shared__ float rs[4], rss[4];
    int wv = threadIdx.x >> 6;
    if ((threadIdx.x & 63) == 0) { rs[wv] = s; rss[wv] = ss; }
    __syncthreads();
    if (threadIdx.x == 0) {
        float S  = rs[0] + rs[1] + rs[2] + rs[3];
        float SS = rss[0] + rss[1] + rss[2] + rss[3];
        const float inv = 1.f / (float)(CPG * HW);
        float mean = S * inv;
        float var  = SS * inv - mean * mean;
        stats[2*bg]   = mean;
        stats[2*bg+1] = rsqrtf(var + EPS);
    }
}

// ---------------- GroupNorm apply (elementwise, float4) ----------------
__global__ __launch_bounds__(256) void gn_apply_k(const float* __restrict__ x,
                                                  const float* __restrict__ gamma,
                                                  const float* __restrict__ beta,
                                                  const float* __restrict__ stats,
                                                  float* __restrict__ h) {
    int idx = blockIdx.x * 256 + threadIdx.x;     // float4 index
    int bc = idx / (HW / 4);                       // b*256+c
    int b = bc >> 8, c = bc & 255;
    int bg = b * NG + (c >> 5);
    float mean = stats[2*bg], rstd = stats[2*bg+1];
    float sc = gamma[c] * rstd;
    float sh = beta[c] - mean * sc;
    float4 v = ((const float4*)x)[idx];
    float4 o;
    o.x = v.x*sc + sh; o.y = v.y*sc + sh; o.z = v.z*sc + sh; o.w = v.w*sc + sh;
    ((float4*)h)[idx] = o;
}

// ---------------- Channel-major GEMM: out[b][m][p] = sum_k A[m][k]*Bm[b][k][p] + bias[m] (+resid) ----------------
// K fixed = 256. Tile 64x64, BK=16, 256 threads, 4x4 microtile.
__global__ __launch_bounds__(256) void gemm_k(const float* __restrict__ A,     // [Mdim][256]
                                              const float* __restrict__ Bm,    // [NB][256][HW]
                                              const float* __restrict__ bias,  // [Mdim]
                                              const float* __restrict__ resid, // [NB][Mdim][HW] or null
                                              float* __restrict__ out,         // [NB][Mdim][HW]
                                              int Mdim) {
    __shared__ float Ast[16][68];  // [k][m] (transposed for vector reads)
    __shared__ float Bs[16][68];   // [k][p]
    int b  = blockIdx.z;
    int my = blockIdx.y;
    int nx = blockIdx.x;
    int t = threadIdx.x;
    int ty = t >> 4, tx = t & 15;
    const float* Ab = A + (size_t)my * 64 * 256;
    const float* Bb = Bm + (size_t)b * 256 * HW + nx * 64;
    float acc[4][4] = {};
    int lr  = t >> 2;         // A row 0..63
    int lc  = (t & 3) * 4;    // A k-offset
    int brr = t >> 4;         // B row 0..15
    int bc4 = (t & 15) * 4;
    for (int k0 = 0; k0 < 256; k0 += 16) {
        float4 av = *(const float4*)(Ab + lr * 256 + k0 + lc);
        float4 bv = *(const float4*)(Bb + (size_t)(k0 + brr) * HW + bc4);
        Ast[lc + 0][lr] = av.x;
        Ast[lc + 1][lr] = av.y;
        Ast[lc + 2][lr] = av.z;
        Ast[lc + 3][lr] = av.w;
        *(float4*)&Bs[brr][bc4] = bv;
        __syncthreads();
        #pragma unroll
        for (int kk = 0; kk < 16; kk++) {
            float4 a4 = *(const float4*)&Ast[kk][ty * 4];
            float4 b4 = *(const float4*)&Bs[kk][tx * 4];
            acc[0][0] += a4.x*b4.x; acc[0][1] += a4.x*b4.y; acc[0][2] += a4.x*b4.z; acc[0][3] += a4.x*b4.w;
            acc[1][0] += a4.y*b4.x; acc[1][1] += a4.y*b4.y; acc[1][2] += a4.y*b4.z; acc[1][3] += a4.y*b4.w;
            acc[2][0] += a4.z*b4.x; acc[2][1] += a4.z*b4.y; acc[2][2] += a4.z*b4.z; acc[2][3] += a4.z*b4.w;
            acc[3][0] += a4.w*b4.x; acc[3][1] += a4.w*b4.y; acc[3][2] += a4.w*b4.z; acc[3][3] += a4.w*b4.w;
        }
        __syncthreads();
    }
    #pragma unroll
    for (int r = 0; r < 4; r++) {
        int m = my * 64 + ty * 4 + r;
        size_t off = ((size_t)b * Mdim + m) * HW + nx * 64 + tx * 4;
        float bsv = bias[m];
        float4 o;
        o.x = acc[r][0] + bsv; o.y = acc[r][1] + bsv; o.z = acc[r][2] + bsv; o.w = acc[r][3] + bsv;
        if (resid != nullptr) {
            float4 rv = *(const float4*)(resid + off);
            o.x += rv.x; o.y += rv.y; o.z += rv.z; o.w += rv.w;
        }
        *(float4*)(out + off) = o;
    }
}

// ---------------- Flash attention, fp32, channel-major ----------------
// qkv layout: [b][o][p], o in [0,768): q at o=h*64+d, k at 256+h*64+d, v at 512+h*64+d.
// Block = one (b, head, i-tile of 64). S kept transposed St[j][i]; O accumulated as O^T[d][i].
__global__ __launch_bounds__(256) void attn_k(const float* __restrict__ qkv,
                                              float* __restrict__ attno) {
    __shared__ float Qs[64][68];   // [d][i], pre-scaled by 1/8
    __shared__ float KVs[64][68];  // [d][j] (K, then V)
    __shared__ float St[64][68];   // [j][i] scores -> probabilities
    __shared__ float mi[64], li[64], al[64];
    int it = blockIdx.x, hh = blockIdx.y, b = blockIdx.z;
    int i0 = it * 64;
    const float* qb = qkv + ((size_t)b * 768 + hh * HD) * HW;
    const float* kb = qb + (size_t)C_ * HW;
    const float* vb = qb + (size_t)2 * C_ * HW;
    int t = threadIdx.x;
    int ty = t >> 4, tx = t & 15;
    int dr = t >> 4;           // loader row 0..15
    int ic = (t & 15) * 4;     // loader col*4
    // load Q [d][i], scaled
    #pragma unroll
    for (int p = 0; p < 4; p++) {
        int d = dr + p * 16;
        float4 v = *(const float4*)(qb + (size_t)d * HW + i0 + ic);
        v.x *= 0.125f; v.y *= 0.125f; v.z *= 0.125f; v.w *= 0.125f;
        *(float4*)&Qs[d][ic] = v;
    }
    if (t < 64) { mi[t] = -INFINITY; li[t] = 0.f; }
    float oacc[4][4] = {};  // O^T[d=ty*4+r][i=tx*4+c]
    __syncthreads();
    for (int jt = 0; jt < 64; jt++) {
        int j0 = jt * 64;
        // load K tile [d][j]
        #pragma unroll
        for (int p = 0; p < 4; p++) {
            int d = dr + p * 16;
            *(float4*)&KVs[d][ic] = *(const float4*)(kb + (size_t)d * HW + j0 + ic);
        }
        __syncthreads();
        // St[j][i] = sum_d K[d][j] * Q[d][i]
        float sacc[4][4] = {};
        #pragma unroll 8
        for (int d = 0; d < 64; d++) {
            float4 k4 = *(const float4*)&KVs[d][ty * 4];
            float4 q4 = *(const float4*)&Qs[d][tx * 4];
            sacc[0][0] += k4.x*q4.x; sacc[0][1] += k4.x*q4.y; sacc[0][2] += k4.x*q4.z; sacc[0][3] += k4.x*q4.w;
            sacc[1][0] += k4.y*q4.x; sacc[1][1] += k4.y*q4.y; sacc[1][2] += k4.y*q4.z; sacc[1][3] += k4.y*q4.w;
            sacc[2][0] += k4.z*q4.x; sacc[2][1] += k4.z*q4.y; sacc[2][2] += k4.z*q4.z; sacc[2][3] += k4.z*q4.w;
            sacc[3][0] += k4.w*q4.x; sacc[3][1] += k4.w*q4.y; sacc[3][2] += k4.w*q4.z; sacc[3][3] += k4.w*q4.w;
        }
        #pragma unroll
        for (int r = 0; r < 4; r++)
            *(float4*)&St[ty * 4 + r][tx * 4] =
                make_float4(sacc[r][0], sacc[r][1], sacc[r][2], sacc[r][3]);
        __syncthreads();
        // load V tile [d][j] (K no longer needed), softmax down St columns
        #pragma unroll
        for (int p = 0; p < 4; p++) {
            int d = dr + p * 16;
            *(float4*)&KVs[d][ic] = *(const float4*)(vb + (size_t)d * HW + j0 + ic);
        }
        {
            int i = t >> 2, seg = t & 3;
            float vals[16];
            float m = -INFINITY;
            #pragma unroll
            for (int jj = 0; jj < 16; jj++) {
                vals[jj] = St[seg * 16 + jj][i];
                m = fmaxf(m, vals[jj]);
            }
            m = fmaxf(m, __shfl_xor(m, 1));
            m = fmaxf(m, __shfl_xor(m, 2));
            float mold = mi[i];
            float mnew = fmaxf(mold, m);
            float ssum = 0.f;
            #pragma unroll
            for (int jj = 0; jj < 16; jj++) {
                float pv = __expf(vals[jj] - mnew);
                ssum += pv;
                St[seg * 16 + jj][i] = pv;
            }
            ssum += __shfl_xor(ssum, 1);
            ssum += __shfl_xor(ssum, 2);
            if (seg == 0) {
                float a = __expf(mold - mnew);
                al[i] = a;
                mi[i] = mnew;
                li[i] = li[i] * a + ssum;
            }
        }
        __syncthreads();
        // O^T[d][i] = O^T*al[i] + sum_j V[d][j] * P[j][i]
        float alr[4];
        #pragma unroll
        for (int c = 0; c < 4; c++) alr[c] = al[tx * 4 + c];
        #pragma unroll
        for (int r = 0; r < 4; r++) {
            oacc[r][0] *= alr[0]; oacc[r][1] *= alr[1];
            oacc[r][2] *= alr[2]; oacc[r][3] *= alr[3];
        }
        #pragma unroll 4
        for (int j4 = 0; j4 < 64; j4 += 4) {
            float4 p0 = *(const float4*)&St[j4 + 0][tx * 4];
            float4 p1 = *(const float4*)&St[j4 + 1][tx * 4];
            float4 p2 = *(const float4*)&St[j4 + 2][tx * 4];
            float4 p3 = *(const float4*)&St[j4 + 3][tx * 4];
            #pragma unroll
            for (int r = 0; r < 4; r++) {
                float4 v = *(const float4*)&KVs[ty * 4 + r][j4];
                oacc[r][0] += v.x*p0.x + v.y*p1.x + v.z*p2.x + v.w*p3.x;
                oacc[r][1] += v.x*p0.y + v.y*p1.y + v.z*p2.y + v.w*p3.y;
                oacc[r][2] += v.x*p0.z + v.y*p1.z + v.z*p2.z + v.w*p3.z;
                oacc[r][3] += v.x*p0.w + v.y*p1.w + v.z*p2.w + v.w*p3.w;
            }
        }
        __syncthreads();
    }
    // epilogue: divide by l, stage O^T[d][i] into Qs, write coalesced
    float linv[4];
    #pragma unroll
    for (int c = 0; c < 4; c++) linv[c] = 1.f / li[tx * 4 + c];
    #pragma unroll
    for (int r = 0; r < 4; r++)
        *(float4*)&Qs[ty * 4 + r][tx * 4] =
            make_float4(oacc[r][0] * linv[0], oacc[r][1] * linv[1],
                        oacc[r][2] * linv[2], oacc[r][3] * linv[3]);
    __syncthreads();
    {
        float* ob = attno + ((size_t)b * C_ + hh * HD) * HW;
        #pragma unroll
        for (int p = 0; p < 4; p++) {
            int d = dr + p * 16;
            *(float4*)(ob + (size_t)d * HW + i0 + ic) = *(const float4*)&Qs[d][ic];
        }
    }
}

extern "C" void kernel_launch(void* const* d_in, const int* in_sizes, int n_in,
                              void* d_out, int out_size, void* d_ws, size_t ws_size,
                              hipStream_t stream) {
    const float* x      = (const float*)d_in[0];
    const float* gamma  = (const float*)d_in[1];
    const float* beta   = (const float*)d_in[2];
    const float* w_qkv  = (const float*)d_in[3];
    const float* b_qkv  = (const float*)d_in[4];
    const float* w_proj = (const float*)d_in[5];
    const float* b_proj = (const float*)d_in[6];
    float* out = (float*)d_out;

    // ws layout (floats): [stats 64 (pad to 256)] [qkv NB*768*HW] [attno NB*256*HW]
    // total = 256 + 12582912 + 4194304 floats = ~64 MB
    float* stats = (float*)d_ws;
    float* qkv   = stats + 256;
    float* attno = qkv + (size_t)NB * 3 * C_ * HW;
    float* h     = out;  // reuse d_out as GroupNorm output; overwritten only by final GEMM

    gn_stats_k<<<32, 256, 0, stream>>>(x, stats);
    gn_apply_k<<<NB * C_ * HW / 4 / 256, 256, 0, stream>>>(x, gamma, beta, stats, h);
    gemm_k<<<dim3(HW / 64, 12, NB), 256, 0, stream>>>(w_qkv, h, b_qkv, nullptr, qkv, 768);
    attn_k<<<dim3(HW / 64, NH, NB), 256, 0, stream>>>(qkv, attno);
    gemm_k<<<dim3(HW / 64, 4, NB), 256, 0, stream>>>(w_proj, attno, b_proj, x, out, 256);
}

// Round 3
// 484.829 us; speedup vs baseline: 2.9230x; 2.9230x over previous
//
#include <hip/hip_runtime.h>
#include <math.h>

#define NB 4
#define C_ 256
#define NG 8
#define CPG 32
#define HW 4096
#define NH 4
#define HD 64
#define EPS 1e-5f
#define QSCALE 0.1803368801111204f  /* 0.125 * log2(e): folds 1/sqrt(64) and base-2 softmax */

typedef __attribute__((ext_vector_type(8))) short bf16x8_t;
typedef __attribute__((ext_vector_type(4))) float f32x4_t;

__device__ __forceinline__ unsigned short f2bf(float f) {
    unsigned u = __float_as_uint(f);
    u += 0x7FFFu + ((u >> 16) & 1u);   // RNE
    return (unsigned short)(u >> 16);
}

// ---------------- GroupNorm stats: one block per (b,g); group data is contiguous ----------------
__global__ __launch_bounds__(256) void gn_stats_k(const float* __restrict__ x,
                                                  float* __restrict__ stats) {
    int bg = blockIdx.x;  // 0..31
    const float4* base = (const float4*)(x + (size_t)bg * CPG * HW);
    const int n4 = CPG * HW / 4;  // 32768
    float s = 0.f, ss = 0.f;
    for (int i = threadIdx.x; i < n4; i += 256) {
        float4 v = base[i];
        s  += v.x + v.y + v.z + v.w;
        ss += v.x*v.x + v.y*v.y + v.z*v.z + v.w*v.w;
    }
    #pragma unroll
    for (int off = 32; off > 0; off >>= 1) {
        s  += __shfl_down(s, off);
        ss += __shfl_down(ss, off);
    }
    __shared__ float rs[4], rss[4];
    int wv = threadIdx.x >> 6;
    if ((threadIdx.x & 63) == 0) { rs[wv] = s; rss[wv] = ss; }
    __syncthreads();
    if (threadIdx.x == 0) {
        float S  = rs[0] + rs[1] + rs[2] + rs[3];
        float SS = rss[0] + rss[1] + rss[2] + rss[3];
        const float inv = 1.f / (float)(CPG * HW);
        float mean = S * inv;
        float var  = SS * inv - mean * mean;
        stats[2*bg]   = mean;
        stats[2*bg+1] = rsqrtf(var + EPS);
    }
}

// ---------------- GroupNorm apply (elementwise, float4) ----------------
__global__ __launch_bounds__(256) void gn_apply_k(const float* __restrict__ x,
                                                  const float* __restrict__ gamma,
                                                  const float* __restrict__ beta,
                                                  const float* __restrict__ stats,
                                                  float* __restrict__ h) {
    int idx = blockIdx.x * 256 + threadIdx.x;     // float4 index
    int bc = idx / (HW / 4);                       // b*256+c
    int b = bc >> 8, c = bc & 255;
    int bg = b * NG + (c >> 5);
    float mean = stats[2*bg], rstd = stats[2*bg+1];
    float sc = gamma[c] * rstd;
    float sh = beta[c] - mean * sc;
    float4 v = ((const float4*)x)[idx];
    float4 o;
    o.x = v.x*sc + sh; o.y = v.y*sc + sh; o.z = v.z*sc + sh; o.w = v.w*sc + sh;
    ((float4*)h)[idx] = o;
}

// ---------------- fp32 GEMM (used for proj): out[b][m][p] = A[m][:]·Bm[b][:][p] + bias[m] (+resid) ----------------
__global__ __launch_bounds__(256) void gemm_k(const float* __restrict__ A,
                                              const float* __restrict__ Bm,
                                              const float* __restrict__ bias,
                                              const float* __restrict__ resid,
                                              float* __restrict__ out,
                                              int Mdim) {
    __shared__ float Ast[16][68];
    __shared__ float Bs[16][68];
    int b  = blockIdx.z;
    int my = blockIdx.y;
    int nx = blockIdx.x;
    int t = threadIdx.x;
    int ty = t >> 4, tx = t & 15;
    const float* Ab = A + (size_t)my * 64 * 256;
    const float* Bb = Bm + (size_t)b * 256 * HW + nx * 64;
    float acc[4][4] = {};
    int lr  = t >> 2;
    int lc  = (t & 3) * 4;
    int brr = t >> 4;
    int bc4 = (t & 15) * 4;
    for (int k0 = 0; k0 < 256; k0 += 16) {
        float4 av = *(const float4*)(Ab + lr * 256 + k0 + lc);
        float4 bv = *(const float4*)(Bb + (size_t)(k0 + brr) * HW + bc4);
        Ast[lc + 0][lr] = av.x;
        Ast[lc + 1][lr] = av.y;
        Ast[lc + 2][lr] = av.z;
        Ast[lc + 3][lr] = av.w;
        *(float4*)&Bs[brr][bc4] = bv;
        __syncthreads();
        #pragma unroll
        for (int kk = 0; kk < 16; kk++) {
            float4 a4 = *(const float4*)&Ast[kk][ty * 4];
            float4 b4 = *(const float4*)&Bs[kk][tx * 4];
            acc[0][0] += a4.x*b4.x; acc[0][1] += a4.x*b4.y; acc[0][2] += a4.x*b4.z; acc[0][3] += a4.x*b4.w;
            acc[1][0] += a4.y*b4.x; acc[1][1] += a4.y*b4.y; acc[1][2] += a4.y*b4.z; acc[1][3] += a4.y*b4.w;
            acc[2][0] += a4.z*b4.x; acc[2][1] += a4.z*b4.y; acc[2][2] += a4.z*b4.z; acc[2][3] += a4.z*b4.w;
            acc[3][0] += a4.w*b4.x; acc[3][1] += a4.w*b4.y; acc[3][2] += a4.w*b4.z; acc[3][3] += a4.w*b4.w;
        }
        __syncthreads();
    }
    #pragma unroll
    for (int r = 0; r < 4; r++) {
        int m = my * 64 + ty * 4 + r;
        size_t off = ((size_t)b * Mdim + m) * HW + nx * 64 + tx * 4;
        float bsv = bias[m];
        float4 o;
        o.x = acc[r][0] + bsv; o.y = acc[r][1] + bsv; o.z = acc[r][2] + bsv; o.w = acc[r][3] + bsv;
        if (resid != nullptr) {
            float4 rv = *(const float4*)(resid + off);
            o.x += rv.x; o.y += rv.y; o.z += rv.z; o.w += rv.w;
        }
        *(float4*)(out + off) = o;
    }
}

// ---------------- QKV GEMM (fp32 math) with bf16 multi-layout epilogue ----------------
// my 0..3: Q head my  -> qt[(b,h)][p][d] bf16, scaled by QSCALE (transposed via LDS)
// my 4..7: K head my-4-> kt[(b,h)][p][d] bf16 (transposed via LDS)
// my 8..11:V head my-8-> vv[(b,h)][d][p] bf16 (direct)
__global__ __launch_bounds__(256) void gemm_qkv_k(const float* __restrict__ A,     // w_qkv [768][256]
                                                  const float* __restrict__ Bm,    // h [NB][256][HW]
                                                  const float* __restrict__ bias,  // [768]
                                                  unsigned short* __restrict__ qt,
                                                  unsigned short* __restrict__ kt,
                                                  unsigned short* __restrict__ vv) {
    __shared__ float Ast[16][68];
    __shared__ float Bs[16][68];
    __shared__ unsigned short T[64][72];   // [p][d] staging, 144B rows (16B aligned)
    int b  = blockIdx.z;
    int my = blockIdx.y;   // 0..11
    int nx = blockIdx.x;
    int t = threadIdx.x;
    int ty = t >> 4, tx = t & 15;
    const float* Ab = A + (size_t)my * 64 * 256;
    const float* Bb = Bm + (size_t)b * 256 * HW + nx * 64;
    float acc[4][4] = {};
    int lr  = t >> 2;
    int lc  = (t & 3) * 4;
    int brr = t >> 4;
    int bc4 = (t & 15) * 4;
    for (int k0 = 0; k0 < 256; k0 += 16) {
        float4 av = *(const float4*)(Ab + lr * 256 + k0 + lc);
        float4 bv = *(const float4*)(Bb + (size_t)(k0 + brr) * HW + bc4);
        Ast[lc + 0][lr] = av.x;
        Ast[lc + 1][lr] = av.y;
        Ast[lc + 2][lr] = av.z;
        Ast[lc + 3][lr] = av.w;
        *(float4*)&Bs[brr][bc4] = bv;
        __syncthreads();
        #pragma unroll
        for (int kk = 0; kk < 16; kk++) {
            float4 a4 = *(const float4*)&Ast[kk][ty * 4];
            float4 b4 = *(const float4*)&Bs[kk][tx * 4];
            acc[0][0] += a4.x*b4.x; acc[0][1] += a4.x*b4.y; acc[0][2] += a4.x*b4.z; acc[0][3] += a4.x*b4.w;
            acc[1][0] += a4.y*b4.x; acc[1][1] += a4.y*b4.y; acc[1][2] += a4.y*b4.z; acc[1][3] += a4.y*b4.w;
            acc[2][0] += a4.z*b4.x; acc[2][1] += a4.z*b4.y; acc[2][2] += a4.z*b4.z; acc[2][3] += a4.z*b4.w;
            acc[3][0] += a4.w*b4.x; acc[3][1] += a4.w*b4.y; acc[3][2] += a4.w*b4.z; acc[3][3] += a4.w*b4.w;
        }
        __syncthreads();
    }
    int sec = my >> 2;        // 0=q, 1=k, 2=v
    int hh  = my & 3;
    if (sec == 2) {
        // V: direct [d][p] bf16 store
        #pragma unroll
        for (int r = 0; r < 4; r++) {
            int d = ty * 4 + r;
            float bsv = bias[my * 64 + d];
            size_t off = ((size_t)(b * NH + hh) * 64 + d) * HW + nx * 64 + tx * 4;
            ushort4 o;
            o.x = f2bf(acc[r][0] + bsv); o.y = f2bf(acc[r][1] + bsv);
            o.z = f2bf(acc[r][2] + bsv); o.w = f2bf(acc[r][3] + bsv);
            *(ushort4*)(vv + off) = o;
        }
    } else {
        // Q/K: transpose through LDS -> [p][d] bf16
        float sc = (sec == 0) ? QSCALE : 1.f;
        #pragma unroll
        for (int r = 0; r < 4; r++) {
            float bsv = bias[my * 64 + ty * 4 + r];
            #pragma unroll
            for (int c = 0; c < 4; c++)
                T[tx * 4 + c][ty * 4 + r] = f2bf((acc[r][c] + bsv) * sc);
        }
        __syncthreads();
        unsigned short* dst = ((sec == 0) ? qt : kt) + ((size_t)(b * NH + hh) * HW + nx * 64) * 64;
        int p = t >> 2, cc = t & 3;
        *(uint4*)(dst + p * 64 + cc * 16)     = *(const uint4*)&T[p][cc * 16];
        *(uint4*)(dst + p * 64 + cc * 16 + 8) = *(const uint4*)&T[p][cc * 16 + 8];
    }
}

// ---------------- Flash attention, bf16 MFMA ----------------
// qt,kt: [(b,h)][p][64] bf16 (Q pre-scaled by QSCALE); vv: [(b,h)][64][p] bf16.
// Block: 128-query tile, 4 waves; wave w owns i-strip [w*32, w*32+32) -> softmax state & Pt rows wave-private.
// K/V 64-j tiles staged to LDS with XOR-swizzled 16B chunks: slot(row,c) = row*8 + (c ^ (row&7)).
// NOTE: the P (and alpha) LDS round-trip MUST be fenced by __syncthreads() — without it the
// compiler hoists the bf16x8 P-fragment ds_reads above the ushort P ds_writes (TBAA no-alias)
// and PV consumes stale/uninitialized LDS (round-2 failure, absmax ~95).
__global__ __launch_bounds__(256) void attn_k(const unsigned short* __restrict__ qt,
                                              const unsigned short* __restrict__ kt,
                                              const unsigned short* __restrict__ vv,
                                              float* __restrict__ attno) {
    __shared__ unsigned short Klds[4096];   // 64 rows(j) x 64(d), swizzled
    __shared__ unsigned short Vlds[4096];   // 64 rows(d) x 64(j), swizzled
    __shared__ unsigned short Pt[128][72];  // [i][j] bf16, 144B pitch
    __shared__ float al_s[128];
    int t = threadIdx.x;
    int wave = t >> 6, lane = t & 63, quad = lane >> 4, l16 = lane & 15;
    int I = wave * 32;
    int i0 = blockIdx.x * 128;
    int hh = blockIdx.y, b = blockIdx.z;
    const unsigned short* qb  = qt + (size_t)(b * NH + hh) * HW * 64;
    const unsigned short* kbp = kt + (size_t)(b * NH + hh) * HW * 64;
    const unsigned short* vbp = vv + (size_t)(b * NH + hh) * 64 * HW;

    // Q fragments (A operand): rows i = i0+I+mi*16+l16, k-chunks kbi*32+quad*8 — live in regs all kernel
    bf16x8_t qf[2][2];
    #pragma unroll
    for (int mi = 0; mi < 2; mi++)
        #pragma unroll
        for (int kbi = 0; kbi < 2; kbi++)
            qf[mi][kbi] = *(const bf16x8_t*)(qb + (size_t)(i0 + I + mi * 16 + l16) * 64 + kbi * 32 + quad * 8);

    f32x4_t oacc[4][2];
    const f32x4_t zz = {0.f, 0.f, 0.f, 0.f};
    #pragma unroll
    for (int d_ = 0; d_ < 4; d_++) { oacc[d_][0] = zz; oacc[d_][1] = zz; }
    float m_pr[2][4], l_sum[2][4];
    #pragma unroll
    for (int mi = 0; mi < 2; mi++)
        #pragma unroll
        for (int r = 0; r < 4; r++) { m_pr[mi][r] = -INFINITY; l_sum[mi][r] = 0.f; }

    // staging maps (constant per thread)
    int soffK[2], soffV[2], slds[2];
    #pragma unroll
    for (int n = 0; n < 2; n++) {
        int s = n * 256 + t;
        int row = s >> 3;
        int c = (s & 7) ^ (row & 7);
        soffK[n] = row * 128 + c * 16;          // bytes in K tile (row=j, 128B rows)
        soffV[n] = row * (HW * 2) + c * 16;     // bytes (row=d, stride HW*2)
        slds[n] = s * 8;                        // ushort index
    }
    uint4 kreg[2], vreg[2];
    {
        const char* kbase = (const char*)kbp;
        const char* vbase = (const char*)vbp;
        kreg[0] = *(const uint4*)(kbase + soffK[0]); kreg[1] = *(const uint4*)(kbase + soffK[1]);
        vreg[0] = *(const uint4*)(vbase + soffV[0]); vreg[1] = *(const uint4*)(vbase + soffV[1]);
    }

    for (int jt = 0; jt < 64; jt++) {
        __syncthreads();   // previous tile fully consumed
        *(uint4*)&Klds[slds[0]] = kreg[0]; *(uint4*)&Klds[slds[1]] = kreg[1];
        *(uint4*)&Vlds[slds[0]] = vreg[0]; *(uint4*)&Vlds[slds[1]] = vreg[1];
        __syncthreads();   // tiles ready
        if (jt < 63) {     // prefetch next tile into regs; latency hidden behind compute
            const char* kbase = (const char*)kbp + (size_t)(jt + 1) * 8192;
            const char* vbase = (const char*)vbp + (size_t)(jt + 1) * 128;
            kreg[0] = *(const uint4*)(kbase + soffK[0]); kreg[1] = *(const uint4*)(kbase + soffK[1]);
            vreg[0] = *(const uint4*)(vbase + soffV[0]); vreg[1] = *(const uint4*)(vbase + soffV[1]);
        }

        // ---- QK^T: S[i][j], D rows = i (quad*4+r), cols = j (l16) ----
        f32x4_t sacc[2][4];
        #pragma unroll
        for (int mi = 0; mi < 2; mi++)
            #pragma unroll
            for (int nj = 0; nj < 4; nj++) sacc[mi][nj] = zz;
        #pragma unroll
        for (int nj = 0; nj < 4; nj++) {
            int j = nj * 16 + l16;
            int rb = j * 8;
            bf16x8_t kf0 = *(const bf16x8_t*)&Klds[(rb + ((quad    ) ^ (j & 7))) * 8];
            bf16x8_t kf1 = *(const bf16x8_t*)&Klds[(rb + ((4 + quad) ^ (j & 7))) * 8];
            #pragma unroll
            for (int mi = 0; mi < 2; mi++) {
                sacc[mi][nj] = __builtin_amdgcn_mfma_f32_16x16x32_bf16(qf[mi][0], kf0, sacc[mi][nj], 0, 0, 0);
                sacc[mi][nj] = __builtin_amdgcn_mfma_f32_16x16x32_bf16(qf[mi][1], kf1, sacc[mi][nj], 0, 0, 0);
            }
        }

        // ---- online softmax (base-2; scale folded into Q) ----
        float alpha[2][4];
        #pragma unroll
        for (int mi = 0; mi < 2; mi++) {
            #pragma unroll
            for (int r = 0; r < 4; r++) {
                float m = fmaxf(fmaxf(sacc[mi][0][r], sacc[mi][1][r]),
                                fmaxf(sacc[mi][2][r], sacc[mi][3][r]));
                m = fmaxf(m, __shfl_xor(m, 1));
                m = fmaxf(m, __shfl_xor(m, 2));
                m = fmaxf(m, __shfl_xor(m, 4));
                m = fmaxf(m, __shfl_xor(m, 8));
                float mnew = fmaxf(m_pr[mi][r], m);
                float a = __builtin_amdgcn_exp2f(m_pr[mi][r] - mnew);
                alpha[mi][r] = a;
                float rs = 0.f;
                #pragma unroll
                for (int nj = 0; nj < 4; nj++) {
                    float p = __builtin_amdgcn_exp2f(sacc[mi][nj][r] - mnew);
                    sacc[mi][nj][r] = p;
                    rs += p;
                }
                rs += __shfl_xor(rs, 1);
                rs += __shfl_xor(rs, 2);
                rs += __shfl_xor(rs, 4);
                rs += __shfl_xor(rs, 8);
                l_sum[mi][r] = l_sum[mi][r] * a + rs;
                m_pr[mi][r] = mnew;
            }
        }
        // P -> LDS [i][j] (wave-private rows), alpha -> al_s
        #pragma unroll
        for (int mi = 0; mi < 2; mi++)
            #pragma unroll
            for (int r = 0; r < 4; r++) {
                int row = I + mi * 16 + quad * 4 + r;
                #pragma unroll
                for (int nj = 0; nj < 4; nj++)
                    Pt[row][nj * 16 + l16] = f2bf(sacc[mi][nj][r]);
            }
        if (l16 == 0) {
            #pragma unroll
            for (int mi = 0; mi < 2; mi++)
                #pragma unroll
                for (int r = 0; r < 4; r++)
                    al_s[I + mi * 16 + quad * 4 + r] = alpha[mi][r];
        }
        __syncthreads();   // FENCE: P/alpha writes must land before fragment reads (see note)

        // ---- PV: O^T[d][i] += V[d][:]·P[:][i]; rescale O by alpha first ----
        bf16x8_t pf[2][2];
        #pragma unroll
        for (int ni = 0; ni < 2; ni++)
            #pragma unroll
            for (int kb2 = 0; kb2 < 2; kb2++)
                pf[ni][kb2] = *(const bf16x8_t*)&Pt[I + ni * 16 + l16][kb2 * 32 + quad * 8];
        float alv0 = al_s[I + l16];
        float alv1 = al_s[I + 16 + l16];
        #pragma unroll
        for (int d_ = 0; d_ < 4; d_++) { oacc[d_][0] *= alv0; oacc[d_][1] *= alv1; }
        #pragma unroll
        for (int d_ = 0; d_ < 4; d_++) {
            int d = d_ * 16 + l16;
            int rb = d * 8;
            bf16x8_t vf0 = *(const bf16x8_t*)&Vlds[(rb + ((quad    ) ^ (d & 7))) * 8];
            bf16x8_t vf1 = *(const bf16x8_t*)&Vlds[(rb + ((4 + quad) ^ (d & 7))) * 8];
            #pragma unroll
            for (int ni = 0; ni < 2; ni++) {
                oacc[d_][ni] = __builtin_amdgcn_mfma_f32_16x16x32_bf16(vf0, pf[ni][0], oacc[d_][ni], 0, 0, 0);
                oacc[d_][ni] = __builtin_amdgcn_mfma_f32_16x16x32_bf16(vf1, pf[ni][1], oacc[d_][ni], 0, 0, 0);
            }
        }
    }

    // ---- epilogue: divide by l, write O^T[d][i] fp32 ----
    if (l16 == 0) {
        #pragma unroll
        for (int mi = 0; mi < 2; mi++)
            #pragma unroll
            for (int r = 0; r < 4; r++)
                al_s[I + mi * 16 + quad * 4 + r] = l_sum[mi][r];
    }
    __syncthreads();   // fence l_sum write -> read
    float linv0 = 1.f / al_s[I + l16];
    float linv1 = 1.f / al_s[I + 16 + l16];
    float* ob = attno + (size_t)(b * NH + hh) * 64 * HW + i0;
    #pragma unroll
    for (int d_ = 0; d_ < 4; d_++)
        #pragma unroll
        for (int ni = 0; ni < 2; ni++) {
            float li = ni ? linv1 : linv0;
            #pragma unroll
            for (int r = 0; r < 4; r++) {
                int d = d_ * 16 + quad * 4 + r;
                ob[(size_t)d * HW + I + ni * 16 + l16] = oacc[d_][ni][r] * li;
            }
        }
}

extern "C" void kernel_launch(void* const* d_in, const int* in_sizes, int n_in,
                              void* d_out, int out_size, void* d_ws, size_t ws_size,
                              hipStream_t stream) {
    const float* x      = (const float*)d_in[0];
    const float* gamma  = (const float*)d_in[1];
    const float* beta   = (const float*)d_in[2];
    const float* w_qkv  = (const float*)d_in[3];
    const float* b_qkv  = (const float*)d_in[4];
    const float* w_proj = (const float*)d_in[5];
    const float* b_proj = (const float*)d_in[6];
    float* out = (float*)d_out;

    // ws (floats/halves): stats[256] | attno fp32 [4M] | qt bf16 [4M] | kt bf16 [4M] | vv bf16 [4M]  => ~41 MB
    float* stats = (float*)d_ws;
    float* attno = stats + 256;
    unsigned short* qt = (unsigned short*)(attno + (size_t)NB * C_ * HW);
    unsigned short* kt = qt + (size_t)NB * NH * HW * 64;
    unsigned short* vv = kt + (size_t)NB * NH * HW * 64;
    float* h = out;  // reuse d_out as GroupNorm output; consumed by gemm_qkv, overwritten by final GEMM

    gn_stats_k<<<32, 256, 0, stream>>>(x, stats);
    gn_apply_k<<<NB * C_ * HW / 4 / 256, 256, 0, stream>>>(x, gamma, beta, stats, h);
    gemm_qkv_k<<<dim3(HW / 64, 12, NB), 256, 0, stream>>>(w_qkv, h, b_qkv, qt, kt, vv);
    attn_k<<<dim3(HW / 128, NH, NB), 256, 0, stream>>>(qt, kt, vv, attno);
    gemm_k<<<dim3(HW / 64, 4, NB), 256, 0, stream>>>(w_proj, attno, b_proj, x, out, 256);
}

// Round 4
// 460.780 us; speedup vs baseline: 3.0756x; 1.0522x over previous
//
#include <hip/hip_runtime.h>
#include <math.h>

#define NB 4
#define C_ 256
#define NG 8
#define CPG 32
#define HW 4096
#define NH 4
#define HD 64
#define EPS 1e-5f
#define QSCALE 0.1803368801111204f  /* 0.125 * log2(e): folds 1/sqrt(64) and base-2 softmax */

typedef __attribute__((ext_vector_type(8))) short bf16x8_t;
typedef __attribute__((ext_vector_type(4))) float f32x4_t;

__device__ __forceinline__ unsigned short f2bf(float f) {
    unsigned u = __float_as_uint(f);
    u += 0x7FFFu + ((u >> 16) & 1u);   // RNE
    return (unsigned short)(u >> 16);
}

// ---------------- GroupNorm stats: one block per (b,g); group data is contiguous ----------------
__global__ __launch_bounds__(256) void gn_stats_k(const float* __restrict__ x,
                                                  float* __restrict__ stats) {
    int bg = blockIdx.x;  // 0..31
    const float4* base = (const float4*)(x + (size_t)bg * CPG * HW);
    const int n4 = CPG * HW / 4;  // 32768
    float s = 0.f, ss = 0.f;
    for (int i = threadIdx.x; i < n4; i += 256) {
        float4 v = base[i];
        s  += v.x + v.y + v.z + v.w;
        ss += v.x*v.x + v.y*v.y + v.z*v.z + v.w*v.w;
    }
    #pragma unroll
    for (int off = 32; off > 0; off >>= 1) {
        s  += __shfl_down(s, off);
        ss += __shfl_down(ss, off);
    }
    __shared__ float rs[4], rss[4];
    int wv = threadIdx.x >> 6;
    if ((threadIdx.x & 63) == 0) { rs[wv] = s; rss[wv] = ss; }
    __syncthreads();
    if (threadIdx.x == 0) {
        float S  = rs[0] + rs[1] + rs[2] + rs[3];
        float SS = rss[0] + rss[1] + rss[2] + rss[3];
        const float inv = 1.f / (float)(CPG * HW);
        float mean = S * inv;
        float var  = SS * inv - mean * mean;
        stats[2*bg]   = mean;
        stats[2*bg+1] = rsqrtf(var + EPS);
    }
}

// ---------------- GroupNorm apply (elementwise, float4) ----------------
__global__ __launch_bounds__(256) void gn_apply_k(const float* __restrict__ x,
                                                  const float* __restrict__ gamma,
                                                  const float* __restrict__ beta,
                                                  const float* __restrict__ stats,
                                                  float* __restrict__ h) {
    int idx = blockIdx.x * 256 + threadIdx.x;     // float4 index
    int bc = idx / (HW / 4);                       // b*256+c
    int b = bc >> 8, c = bc & 255;
    int bg = b * NG + (c >> 5);
    float mean = stats[2*bg], rstd = stats[2*bg+1];
    float sc = gamma[c] * rstd;
    float sh = beta[c] - mean * sc;
    float4 v = ((const float4*)x)[idx];
    float4 o;
    o.x = v.x*sc + sh; o.y = v.y*sc + sh; o.z = v.z*sc + sh; o.w = v.w*sc + sh;
    ((float4*)h)[idx] = o;
}

// ---------------- fp32 GEMM (used for proj): out[b][m][p] = A[m][:]·Bm[b][:][p] + bias[m] (+resid) ----------------
__global__ __launch_bounds__(256) void gemm_k(const float* __restrict__ A,
                                              const float* __restrict__ Bm,
                                              const float* __restrict__ bias,
                                              const float* __restrict__ resid,
                                              float* __restrict__ out,
                                              int Mdim) {
    __shared__ float Ast[16][68];
    __shared__ float Bs[16][68];
    int b  = blockIdx.z;
    int my = blockIdx.y;
    int nx = blockIdx.x;
    int t = threadIdx.x;
    int ty = t >> 4, tx = t & 15;
    const float* Ab = A + (size_t)my * 64 * 256;
    const float* Bb = Bm + (size_t)b * 256 * HW + nx * 64;
    float acc[4][4] = {};
    int lr  = t >> 2;
    int lc  = (t & 3) * 4;
    int brr = t >> 4;
    int bc4 = (t & 15) * 4;
    for (int k0 = 0; k0 < 256; k0 += 16) {
        float4 av = *(const float4*)(Ab + lr * 256 + k0 + lc);
        float4 bv = *(const float4*)(Bb + (size_t)(k0 + brr) * HW + bc4);
        Ast[lc + 0][lr] = av.x;
        Ast[lc + 1][lr] = av.y;
        Ast[lc + 2][lr] = av.z;
        Ast[lc + 3][lr] = av.w;
        *(float4*)&Bs[brr][bc4] = bv;
        __syncthreads();
        #pragma unroll
        for (int kk = 0; kk < 16; kk++) {
            float4 a4 = *(const float4*)&Ast[kk][ty * 4];
            float4 b4 = *(const float4*)&Bs[kk][tx * 4];
            acc[0][0] += a4.x*b4.x; acc[0][1] += a4.x*b4.y; acc[0][2] += a4.x*b4.z; acc[0][3] += a4.x*b4.w;
            acc[1][0] += a4.y*b4.x; acc[1][1] += a4.y*b4.y; acc[1][2] += a4.y*b4.z; acc[1][3] += a4.y*b4.w;
            acc[2][0] += a4.z*b4.x; acc[2][1] += a4.z*b4.y; acc[2][2] += a4.z*b4.z; acc[2][3] += a4.z*b4.w;
            acc[3][0] += a4.w*b4.x; acc[3][1] += a4.w*b4.y; acc[3][2] += a4.w*b4.z; acc[3][3] += a4.w*b4.w;
        }
        __syncthreads();
    }
    #pragma unroll
    for (int r = 0; r < 4; r++) {
        int m = my * 64 + ty * 4 + r;
        size_t off = ((size_t)b * Mdim + m) * HW + nx * 64 + tx * 4;
        float bsv = bias[m];
        float4 o;
        o.x = acc[r][0] + bsv; o.y = acc[r][1] + bsv; o.z = acc[r][2] + bsv; o.w = acc[r][3] + bsv;
        if (resid != nullptr) {
            float4 rv = *(const float4*)(resid + off);
            o.x += rv.x; o.y += rv.y; o.z += rv.z; o.w += rv.w;
        }
        *(float4*)(out + off) = o;
    }
}

// ---------------- QKV GEMM (fp32 math) with bf16 multi-layout epilogue ----------------
// my 0..3: Q head my  -> qt[(b,h)][p][d] bf16, scaled by QSCALE (transposed via LDS)
// my 4..7: K head my-4-> kt[(b,h)][p][d] bf16 (transposed via LDS)
// my 8..11:V head my-8-> vv[(b,h)][d][p] bf16 (direct)
__global__ __launch_bounds__(256) void gemm_qkv_k(const float* __restrict__ A,     // w_qkv [768][256]
                                                  const float* __restrict__ Bm,    // h [NB][256][HW]
                                                  const float* __restrict__ bias,  // [768]
                                                  unsigned short* __restrict__ qt,
                                                  unsigned short* __restrict__ kt,
                                                  unsigned short* __restrict__ vv) {
    __shared__ float Ast[16][68];
    __shared__ float Bs[16][68];
    __shared__ unsigned short T[64][72];   // [p][d] staging, 144B rows (16B aligned)
    int b  = blockIdx.z;
    int my = blockIdx.y;   // 0..11
    int nx = blockIdx.x;
    int t = threadIdx.x;
    int ty = t >> 4, tx = t & 15;
    const float* Ab = A + (size_t)my * 64 * 256;
    const float* Bb = Bm + (size_t)b * 256 * HW + nx * 64;
    float acc[4][4] = {};
    int lr  = t >> 2;
    int lc  = (t & 3) * 4;
    int brr = t >> 4;
    int bc4 = (t & 15) * 4;
    for (int k0 = 0; k0 < 256; k0 += 16) {
        float4 av = *(const float4*)(Ab + lr * 256 + k0 + lc);
        float4 bv = *(const float4*)(Bb + (size_t)(k0 + brr) * HW + bc4);
        Ast[lc + 0][lr] = av.x;
        Ast[lc + 1][lr] = av.y;
        Ast[lc + 2][lr] = av.z;
        Ast[lc + 3][lr] = av.w;
        *(float4*)&Bs[brr][bc4] = bv;
        __syncthreads();
        #pragma unroll
        for (int kk = 0; kk < 16; kk++) {
            float4 a4 = *(const float4*)&Ast[kk][ty * 4];
            float4 b4 = *(const float4*)&Bs[kk][tx * 4];
            acc[0][0] += a4.x*b4.x; acc[0][1] += a4.x*b4.y; acc[0][2] += a4.x*b4.z; acc[0][3] += a4.x*b4.w;
            acc[1][0] += a4.y*b4.x; acc[1][1] += a4.y*b4.y; acc[1][2] += a4.y*b4.z; acc[1][3] += a4.y*b4.w;
            acc[2][0] += a4.z*b4.x; acc[2][1] += a4.z*b4.y; acc[2][2] += a4.z*b4.z; acc[2][3] += a4.z*b4.w;
            acc[3][0] += a4.w*b4.x; acc[3][1] += a4.w*b4.y; acc[3][2] += a4.w*b4.z; acc[3][3] += a4.w*b4.w;
        }
        __syncthreads();
    }
    int sec = my >> 2;        // 0=q, 1=k, 2=v
    int hh  = my & 3;
    if (sec == 2) {
        // V: direct [d][p] bf16 store
        #pragma unroll
        for (int r = 0; r < 4; r++) {
            int d = ty * 4 + r;
            float bsv = bias[my * 64 + d];
            size_t off = ((size_t)(b * NH + hh) * 64 + d) * HW + nx * 64 + tx * 4;
            ushort4 o;
            o.x = f2bf(acc[r][0] + bsv); o.y = f2bf(acc[r][1] + bsv);
            o.z = f2bf(acc[r][2] + bsv); o.w = f2bf(acc[r][3] + bsv);
            *(ushort4*)(vv + off) = o;
        }
    } else {
        // Q/K: transpose through LDS -> [p][d] bf16
        float sc = (sec == 0) ? QSCALE : 1.f;
        #pragma unroll
        for (int r = 0; r < 4; r++) {
            float bsv = bias[my * 64 + ty * 4 + r];
            #pragma unroll
            for (int c = 0; c < 4; c++)
                T[tx * 4 + c][ty * 4 + r] = f2bf((acc[r][c] + bsv) * sc);
        }
        __syncthreads();
        unsigned short* dst = ((sec == 0) ? qt : kt) + ((size_t)(b * NH + hh) * HW + nx * 64) * 64;
        int p = t >> 2, cc = t & 3;
        *(uint4*)(dst + p * 64 + cc * 16)     = *(const uint4*)&T[p][cc * 16];
        *(uint4*)(dst + p * 64 + cc * 16 + 8) = *(const uint4*)&T[p][cc * 16 + 8];
    }
}

// ---------------- Flash attention, bf16 MFMA, S^T orientation ----------------
// qt,kt: [(b,h)][p][64] bf16 (Q pre-scaled by QSCALE); vv: [(b,h)][64][p] bf16.
// Block: 128-query tile, 4 waves; wave w owns i-strip [w*32, w*32+32).
// QK^T computed as S^T = K·Q^T (operand swap; A/B fragments have identical lane maps):
// lane holds S^T[j = nj*16+quad*4+r][i = l16] -> softmax over j is 16 in-lane values +
// 2 butterfly shuffles; m/l/alpha are per-lane-replicated (no LDS state).
// P staged wave-private in fragment-ready chunk order; fenced by __threadfence_block()
// (NOT __syncthreads — same-wave only). K/V staging swizzle as before.
__global__ __launch_bounds__(256) void attn_k(const unsigned short* __restrict__ qt,
                                              const unsigned short* __restrict__ kt,
                                              const unsigned short* __restrict__ vv,
                                              float* __restrict__ attno) {
    __shared__ unsigned short Klds[4096];   // 64 rows(j) x 64(d), swizzled 16B chunks
    __shared__ unsigned short Vlds[4096];   // 64 rows(d) x 64(j), swizzled
    __shared__ unsigned short Pt2[8192];    // [wave][ni][kb][chunk 0..63][8] fragment-ready
    int t = threadIdx.x;
    int wave = t >> 6, lane = t & 63, quad = lane >> 4, l16 = lane & 15;
    int I = wave * 32;
    int i0 = blockIdx.x * 128;
    int hh = blockIdx.y, b = blockIdx.z;
    const unsigned short* qb  = qt + (size_t)(b * NH + hh) * HW * 64;
    const unsigned short* kbp = kt + (size_t)(b * NH + hh) * HW * 64;
    const unsigned short* vbp = vv + (size_t)(b * NH + hh) * 64 * HW;

    // Q fragments: lane holds Q[i = i0+I+mi*16+l16][d = kbi*32+quad*8 ..+8] — B operand for S^T
    bf16x8_t qf[2][2];
    #pragma unroll
    for (int mi = 0; mi < 2; mi++)
        #pragma unroll
        for (int kbi = 0; kbi < 2; kbi++)
            qf[mi][kbi] = *(const bf16x8_t*)(qb + (size_t)(i0 + I + mi * 16 + l16) * 64 + kbi * 32 + quad * 8);

    f32x4_t oacc[4][2];
    const f32x4_t zz = {0.f, 0.f, 0.f, 0.f};
    #pragma unroll
    for (int d_ = 0; d_ < 4; d_++) { oacc[d_][0] = zz; oacc[d_][1] = zz; }
    float m_pr[2] = {-INFINITY, -INFINITY};
    float l_sum[2] = {0.f, 0.f};

    // staging maps (constant per thread)
    int soffK[2], soffV[2], slds[2];
    #pragma unroll
    for (int n = 0; n < 2; n++) {
        int s = n * 256 + t;
        int row = s >> 3;
        int c = (s & 7) ^ (row & 7);
        soffK[n] = row * 128 + c * 16;          // bytes (row=j, 128B rows)
        soffV[n] = row * (HW * 2) + c * 16;     // bytes (row=d, stride HW*2)
        slds[n] = s * 8;                        // ushort index
    }
    uint4 kreg[2], vreg[2];
    {
        const char* kbase = (const char*)kbp;
        const char* vbase = (const char*)vbp;
        kreg[0] = *(const uint4*)(kbase + soffK[0]); kreg[1] = *(const uint4*)(kbase + soffK[1]);
        vreg[0] = *(const uint4*)(vbase + soffV[0]); vreg[1] = *(const uint4*)(vbase + soffV[1]);
    }

    for (int jt = 0; jt < 64; jt++) {
        __syncthreads();   // previous tile fully consumed
        *(uint4*)&Klds[slds[0]] = kreg[0]; *(uint4*)&Klds[slds[1]] = kreg[1];
        *(uint4*)&Vlds[slds[0]] = vreg[0]; *(uint4*)&Vlds[slds[1]] = vreg[1];
        __syncthreads();   // tiles ready
        if (jt < 63) {     // prefetch next tile into regs
            const char* kbase = (const char*)kbp + (size_t)(jt + 1) * 8192;
            const char* vbase = (const char*)vbp + (size_t)(jt + 1) * 128;
            kreg[0] = *(const uint4*)(kbase + soffK[0]); kreg[1] = *(const uint4*)(kbase + soffK[1]);
            vreg[0] = *(const uint4*)(vbase + soffV[0]); vreg[1] = *(const uint4*)(vbase + soffV[1]);
        }

        // ---- S^T = K·Q^T: D rows = j (quad*4+r), cols = i (l16) ----
        f32x4_t sacc[2][4];
        #pragma unroll
        for (int mi = 0; mi < 2; mi++)
            #pragma unroll
            for (int nj = 0; nj < 4; nj++) sacc[mi][nj] = zz;
        #pragma unroll
        for (int nj = 0; nj < 4; nj++) {
            int j = nj * 16 + l16;        // A-operand row
            int rb = j * 8;
            bf16x8_t kf0 = *(const bf16x8_t*)&Klds[(rb + ((quad    ) ^ (j & 7))) * 8];
            bf16x8_t kf1 = *(const bf16x8_t*)&Klds[(rb + ((4 + quad) ^ (j & 7))) * 8];
            #pragma unroll
            for (int mi = 0; mi < 2; mi++) {
                sacc[mi][nj] = __builtin_amdgcn_mfma_f32_16x16x32_bf16(kf0, qf[mi][0], sacc[mi][nj], 0, 0, 0);
                sacc[mi][nj] = __builtin_amdgcn_mfma_f32_16x16x32_bf16(kf1, qf[mi][1], sacc[mi][nj], 0, 0, 0);
            }
        }

        // ---- online softmax (base-2), per i-tile mi; state per-lane-replicated ----
        float alpha_[2];
        #pragma unroll
        for (int mi = 0; mi < 2; mi++) {
            float m = sacc[mi][0][0];
            #pragma unroll
            for (int nj = 0; nj < 4; nj++)
                #pragma unroll
                for (int r = 0; r < 4; r++) m = fmaxf(m, sacc[mi][nj][r]);
            m = fmaxf(m, __shfl_xor(m, 16));
            m = fmaxf(m, __shfl_xor(m, 32));
            float mnew = fmaxf(m_pr[mi], m);
            float a = __builtin_amdgcn_exp2f(m_pr[mi] - mnew);
            alpha_[mi] = a;
            float rs = 0.f;
            #pragma unroll
            for (int nj = 0; nj < 4; nj++)
                #pragma unroll
                for (int r = 0; r < 4; r++) {
                    float p = __builtin_amdgcn_exp2f(sacc[mi][nj][r] - mnew);
                    sacc[mi][nj][r] = p;
                    rs += p;
                }
            rs += __shfl_xor(rs, 16);
            rs += __shfl_xor(rs, 32);
            l_sum[mi] = l_sum[mi] * a + rs;
            m_pr[mi] = mnew;
        }

        // ---- P -> wave-private LDS, fragment-ready chunk order ----
        // writer (quad,l16,mi,nj) holds P[j=nj*16+quad*4+r][i=mi*16+l16], r=0..3.
        // reader coords: kb=nj>>1, q_r = 2*(nj&1)+(quad>>1), idx0 = 4*(quad&1).
        #pragma unroll
        for (int mi = 0; mi < 2; mi++)
            #pragma unroll
            for (int nj = 0; nj < 4; nj++) {
                unsigned lo = (unsigned)f2bf(sacc[mi][nj][0]) | ((unsigned)f2bf(sacc[mi][nj][1]) << 16);
                unsigned hi = (unsigned)f2bf(sacc[mi][nj][2]) | ((unsigned)f2bf(sacc[mi][nj][3]) << 16);
                int chunk = (2 * (nj & 1) + (quad >> 1)) * 16 + l16;
                unsigned short* bp = &Pt2[(((wave * 2 + mi) * 2) + (nj >> 1)) * 512];
                *(uint2*)&bp[chunk * 8 + 4 * (quad & 1)] = make_uint2(lo, hi);
            }

        // rescale O by alpha (registers only)
        #pragma unroll
        for (int d_ = 0; d_ < 4; d_++) { oacc[d_][0] *= alpha_[0]; oacc[d_][1] *= alpha_[1]; }

        __threadfence_block();   // wave-private P round-trip: fence compiler + lgkm (r2 lesson)

        // ---- PV: O^T[d][i] += V[d][:]·P[:][i] ----
        bf16x8_t pf[2][2];
        #pragma unroll
        for (int ni = 0; ni < 2; ni++)
            #pragma unroll
            for (int kb2 = 0; kb2 < 2; kb2++)
                pf[ni][kb2] = *(const bf16x8_t*)&Pt2[(((wave * 2 + ni) * 2) + kb2) * 512 + lane * 8];
        #pragma unroll
        for (int d_ = 0; d_ < 4; d_++) {
            int d = d_ * 16 + l16;
            int rb = d * 8;
            bf16x8_t vf0 = *(const bf16x8_t*)&Vlds[(rb + ((quad    ) ^ (d & 7))) * 8];
            bf16x8_t vf1 = *(const bf16x8_t*)&Vlds[(rb + ((4 + quad) ^ (d & 7))) * 8];
            #pragma unroll
            for (int ni = 0; ni < 2; ni++) {
                oacc[d_][ni] = __builtin_amdgcn_mfma_f32_16x16x32_bf16(vf0, pf[ni][0], oacc[d_][ni], 0, 0, 0);
                oacc[d_][ni] = __builtin_amdgcn_mfma_f32_16x16x32_bf16(vf1, pf[ni][1], oacc[d_][ni], 0, 0, 0);
            }
        }
    }

    // ---- epilogue: divide by l (register-resident), write O^T[d][i] fp32 ----
    float linv0 = 1.f / l_sum[0];
    float linv1 = 1.f / l_sum[1];
    float* ob = attno + (size_t)(b * NH + hh) * 64 * HW + i0;
    #pragma unroll
    for (int d_ = 0; d_ < 4; d_++)
        #pragma unroll
        for (int ni = 0; ni < 2; ni++) {
            float li = ni ? linv1 : linv0;
            #pragma unroll
            for (int r = 0; r < 4; r++) {
                int d = d_ * 16 + quad * 4 + r;
                ob[(size_t)d * HW + I + ni * 16 + l16] = oacc[d_][ni][r] * li;
            }
        }
}

extern "C" void kernel_launch(void* const* d_in, const int* in_sizes, int n_in,
                              void* d_out, int out_size, void* d_ws, size_t ws_size,
                              hipStream_t stream) {
    const float* x      = (const float*)d_in[0];
    const float* gamma  = (const float*)d_in[1];
    const float* beta   = (const float*)d_in[2];
    const float* w_qkv  = (const float*)d_in[3];
    const float* b_qkv  = (const float*)d_in[4];
    const float* w_proj = (const float*)d_in[5];
    const float* b_proj = (const float*)d_in[6];
    float* out = (float*)d_out;

    // ws: stats[256] | attno fp32 [4M] | qt bf16 [4M] | kt bf16 [4M] | vv bf16 [4M]  => ~41 MB
    float* stats = (float*)d_ws;
    float* attno = stats + 256;
    unsigned short* qt = (unsigned short*)(attno + (size_t)NB * C_ * HW);
    unsigned short* kt = qt + (size_t)NB * NH * HW * 64;
    unsigned short* vv = kt + (size_t)NB * NH * HW * 64;
    float* h = out;  // reuse d_out as GroupNorm output; consumed by gemm_qkv, overwritten by final GEMM

    gn_stats_k<<<32, 256, 0, stream>>>(x, stats);
    gn_apply_k<<<NB * C_ * HW / 4 / 256, 256, 0, stream>>>(x, gamma, beta, stats, h);
    gemm_qkv_k<<<dim3(HW / 64, 12, NB), 256, 0, stream>>>(w_qkv, h, b_qkv, qt, kt, vv);
    attn_k<<<dim3(HW / 128, NH, NB), 256, 0, stream>>>(qt, kt, vv, attno);
    gemm_k<<<dim3(HW / 64, 4, NB), 256, 0, stream>>>(w_proj, attno, b_proj, x, out, 256);
}